// Round 1
// baseline (861.431 us; speedup 1.0000x reference)
//
#include <hip/hip_runtime.h>

// Conv2d 32x128x56x56 -> 32x256x56x56, 3x3, pad 1, stride 1.
// Implicit GEMM on bf16 MFMA 16x16x32:
//   M = co (256), N = p = n*3136 + h*56 + w (100352), K = ci*9 + kh*3 + kw (1152)
//   A[co][k]  = weights (already row-major contiguous in memory!)
//   B[k][p]   = im2col gather of x (contiguous along p within rows, masked halo)
// Block: 256 thr = 4 waves, tile 256co x 112p (two full image rows -> p-tile
// never crosses an image). Wave = 64co x 112p = 4x7 MFMA tiles.
// BK=64 (2 mfma-k per barrier pair), LDS pad 72 shorts (144B) -> 16B-aligned
// ds_read_b128 frags with <=2-way bank aliasing (free per m136).

#define CIN   128
#define COUT  256
#define HWID  56
#define IMG   (HWID*HWID)     // 3136
#define NIMG  32
#define KTOT  (CIN*9)         // 1152
#define BN    112             // p tile: 2 rows
#define BK    64
#define APAD  72              // padded K stride (shorts)
#define NSTEPS (KTOT/BK)      // 18

typedef __attribute__((ext_vector_type(8))) short short8;   // 8 bf16 = 4 VGPRs
typedef __attribute__((ext_vector_type(4))) float float4v;  // MFMA acc

__device__ __forceinline__ unsigned short f2bf(float f) {
    unsigned int u = __builtin_bit_cast(unsigned int, f);
    u += 0x7FFFu + ((u >> 16) & 1u);   // RNE
    return (unsigned short)(u >> 16);
}

__global__ void cvt_w_kernel(const float* __restrict__ w, unsigned short* __restrict__ W2) {
    int i = blockIdx.x * 256 + threadIdx.x;
    if (i < COUT * KTOT) W2[i] = f2bf(w[i]);
}

__global__ void cvt_x_kernel(const float* __restrict__ x, unsigned short* __restrict__ X2) {
    int i = blockIdx.x * 256 + threadIdx.x;       // one float4 per thread
    if (i < NIMG * CIN * IMG / 4) {
        float4 v = ((const float4*)x)[i];
        ushort4 o;
        o.x = f2bf(v.x); o.y = f2bf(v.y); o.z = f2bf(v.z); o.w = f2bf(v.w);
        ((ushort4*)X2)[i] = o;
    }
}

__global__ __launch_bounds__(256, 2)
void conv_mfma_kernel(const unsigned short* __restrict__ X2,
                      const unsigned short* __restrict__ W2,
                      float* __restrict__ out) {
    __shared__ __align__(16) unsigned short As[COUT * APAD]; // [co][k] 36864 B
    __shared__ __align__(16) unsigned short Bs[BN * APAD];   // [p][k]  16128 B

    const int tid  = threadIdx.x;
    const int lane = tid & 63;
    const int wv   = tid >> 6;        // wave id 0..3 -> co block wv*64
    const int l15  = lane & 15;
    const int quad = lane >> 4;

    const int pt    = blockIdx.x;     // 0..895
    const int n_img = pt / 28;
    const int h0    = (pt % 28) * 2;  // rows h0, h0+1

    float4v acc[4][7];
    #pragma unroll
    for (int m = 0; m < 4; ++m)
        #pragma unroll
        for (int n = 0; n < 7; ++n)
            acc[m][n] = (float4v){0.f, 0.f, 0.f, 0.f};

    const unsigned short* xbase = X2 + (long)n_img * (CIN * IMG);

    for (int step = 0; step < NSTEPS; ++step) {
        const int k0 = step * BK;
        __syncthreads();

        // ---- stage A: 256co x 64k, 16B per thread-iter, 8 iters ----
        #pragma unroll
        for (int it = 0; it < 8; ++it) {
            int idx = it * 256 + tid;       // 0..2047
            int co  = idx >> 3;
            int ks  = (idx & 7) * 8;
            uint4 v = *(const uint4*)(W2 + co * KTOT + k0 + ks);
            *(uint4*)(&As[co * APAD + ks]) = v;
        }

        // ---- stage B: im2col gather, 112p x 64k, (p, k-pair) per iter ----
        #pragma unroll
        for (int it = 0; it < 14; ++it) {
            int idx = it * 256 + tid;       // 0..3583
            int p   = idx % 112;
            int kp  = idx / 112;            // 0..31 (pair of k)
            int k   = k0 + kp * 2;
            int prow = p / 56;
            int pcol = p - prow * 56;
            unsigned int pack = 0;
            #pragma unroll
            for (int s = 0; s < 2; ++s) {
                int kk = k + s;
                int ci = kk / 9;
                int r9 = kk - ci * 9;
                int kh = r9 / 3;
                int kw = r9 - kh * 3;
                int h  = h0 + prow + kh - 1;
                int w  = pcol + kw - 1;
                unsigned short v = 0;
                if ((unsigned)h < 56u && (unsigned)w < 56u)
                    v = xbase[ci * IMG + h * HWID + w];
                pack |= ((unsigned int)v) << (16 * s);
            }
            *(unsigned int*)(&Bs[p * APAD + kp * 2]) = pack;
        }

        __syncthreads();

        // ---- compute: 2 k-subs x (4m x 7n) MFMA ----
        #pragma unroll
        for (int ks = 0; ks < 2; ++ks) {
            short8 a[4], b[7];
            #pragma unroll
            for (int m = 0; m < 4; ++m)
                a[m] = *(const short8*)(&As[(wv * 64 + m * 16 + l15) * APAD + ks * 32 + quad * 8]);
            #pragma unroll
            for (int n = 0; n < 7; ++n)
                b[n] = *(const short8*)(&Bs[(n * 16 + l15) * APAD + ks * 32 + quad * 8]);
            #pragma unroll
            for (int m = 0; m < 4; ++m)
                #pragma unroll
                for (int n = 0; n < 7; ++n)
                    acc[m][n] = __builtin_amdgcn_mfma_f32_16x16x32_bf16(a[m], b[n], acc[m][n], 0, 0, 0);
        }
    }

    // ---- epilogue: C/D layout col(p)=lane&15, row(co)=quad*4+reg ----
    float* obase = out + (long)n_img * (COUT * IMG) + h0 * HWID;
    #pragma unroll
    for (int m = 0; m < 4; ++m) {
        #pragma unroll
        for (int r = 0; r < 4; ++r) {
            int co = wv * 64 + m * 16 + quad * 4 + r;
            float* orow = obase + (long)co * IMG;
            #pragma unroll
            for (int n = 0; n < 7; ++n)
                orow[n * 16 + l15] = acc[m][n][r];
        }
    }
}

extern "C" void kernel_launch(void* const* d_in, const int* in_sizes, int n_in,
                              void* d_out, int out_size, void* d_ws, size_t ws_size,
                              hipStream_t stream) {
    const float* x  = (const float*)d_in[0];
    const float* wt = (const float*)d_in[1];
    float* out = (float*)d_out;

    unsigned short* X2 = (unsigned short*)d_ws;                 // 12,845,056 bf16
    unsigned short* W2 = X2 + (long)NIMG * CIN * IMG;           // 294,912 bf16

    int nx4 = NIMG * CIN * IMG / 4;                             // 3,211,264
    cvt_x_kernel<<<(nx4 + 255) / 256, 256, 0, stream>>>(x, X2);
    cvt_w_kernel<<<(COUT * KTOT + 255) / 256, 256, 0, stream>>>(wt, W2);
    conv_mfma_kernel<<<896, 256, 0, stream>>>(X2, W2, out);
}

// Round 2
// 205.809 us; speedup vs baseline: 4.1856x; 4.1856x over previous
//
#include <hip/hip_runtime.h>

// Conv2d 32x128x56x56 -> 32x256x56x56, 3x3, pad 1, stride 1. fp32 I/O.
// Implicit GEMM, bf16 mfma_f32_16x16x32. K reordered as (ci_hi, kh*kw, ci_lo):
//  - X pre-transformed to NHWC bf16: B-fragment = 8 consecutive ci = 16B.
//  - W pre-arranged as W2[step][co][ci_lo] (step = ci_hi*9+khw): A-fragments
//    load DIRECTLY global->registers, perfectly coalesced 1KB/wave, L2-hot.
//  - Per ci_hi: stage raw x tile (4 rows x 58 cols x 32 ci, halo zeroed) in
//    LDS once; 9 khw positions read b-frags at immediate offsets -> NO
//    barriers inside the khw loop (8 barriers total vs 36 before).
// Block: 256 thr = 4 waves, tile 256co x 112p (2 output rows). Wave: 4m x 7n.
// LDS col stride 40 shorts (80B): 16B-aligned ds_read_b128, ~2-way banks.

#define CIN   128
#define COUT  256
#define HWID  56
#define IMG   (HWID*HWID)     // 3136
#define NIMG  32
#define CSTR  40              // Bs ci stride (shorts), 80B: 16B-aligned, 2-way banks
#define BROW  (58*CSTR)       // Bs row stride (shorts)

typedef __attribute__((ext_vector_type(8))) short short8;   // 8 bf16 = 4 VGPRs
typedef __attribute__((ext_vector_type(4))) float float4v;  // MFMA acc

__device__ __forceinline__ unsigned short f2bf(float f) {
    unsigned int u = __builtin_bit_cast(unsigned int, f);
    u += 0x7FFFu + ((u >> 16) & 1u);   // RNE
    return (unsigned short)(u >> 16);
}

// W2[((ci_hi*9 + kh*3 + kw)*256 + co)*32 + ci_lo] = bf16(w[co][ci_hi*32+ci_lo][kh][kw])
__global__ void prep_w_kernel(const float* __restrict__ w, unsigned short* __restrict__ W2) {
    int o = blockIdx.x * 256 + threadIdx.x;        // 294912 total
    int ci_lo = o & 31;
    int co    = (o >> 5) & 255;
    int s     = o >> 13;                           // 0..35
    int ci_hi = s / 9;
    int r9    = s - ci_hi * 9;                     // kh*3+kw
    W2[o] = f2bf(w[(co * CIN + ci_hi * 32 + ci_lo) * 9 + r9]);
}

// NCHW fp32 -> NHWC bf16 via LDS tile transpose. Tile: 32 ci x 64 p per block.
__global__ void prep_x_kernel(const float* __restrict__ x, unsigned short* __restrict__ X2) {
    __shared__ unsigned short Ls[32 * 65];
    int b  = blockIdx.x;               // n*(4*49) + cb*49 + pb
    int pb = b % 49;
    int t  = b / 49;
    int cb = t & 3;
    int n  = t >> 2;
    int p0 = pb * 64, ci0 = cb * 32;

    const float* src = x + ((long)n * CIN + ci0) * IMG + p0;
    #pragma unroll
    for (int it = 0; it < 8; ++it) {
        int flat = it * 256 + threadIdx.x;
        int ci_l = flat >> 6, p_l = flat & 63;
        Ls[ci_l * 65 + p_l] = f2bf(src[ci_l * IMG + p_l]);   // coalesced read
    }
    __syncthreads();
    unsigned short* dst = X2 + ((long)n * IMG + p0) * CIN + ci0;
    #pragma unroll
    for (int it = 0; it < 8; ++it) {
        int flat = it * 256 + threadIdx.x;
        int ci_l = flat & 31, p_l = flat >> 5;
        dst[(long)p_l * CIN + ci_l] = Ls[ci_l * 65 + p_l];   // coalesced write
    }
}

__global__ __launch_bounds__(256, 2)
void conv_mfma_kernel(const unsigned short* __restrict__ X2,
                      const unsigned short* __restrict__ W2,
                      float* __restrict__ out) {
    __shared__ __align__(16) unsigned short Bs[4 * BROW];   // 4 rows x 58 cols x 40 ci: 18560 B

    const int tid  = threadIdx.x;
    const int lane = tid & 63;
    const int wv   = tid >> 6;
    const int l15  = lane & 15;
    const int quad = lane >> 4;

    const int pt    = blockIdx.x;      // 0..895
    const int n_img = pt / 28;
    const int h0    = (pt % 28) * 2;   // output rows h0, h0+1

    // per-lane b-frag bases (short index into Bs), one per n-tile
    int boff[7];
    #pragma unroll
    for (int n = 0; n < 7; ++n) {
        int p    = n * 16 + l15;
        int prow = (p >= 56) ? 1 : 0;
        int pcol = p - prow * 56;
        boff[n]  = (prow * 58 + pcol) * CSTR + quad * 8;
    }

    // a-frag base: W2[step][co][ci_lo], co = wv*64 + m*16 + l15, ci_lo = quad*8+j
    const unsigned short* wbase = W2 + (wv * 64 + l15) * 32 + quad * 8;

    float4v acc[4][7];
    #pragma unroll
    for (int m = 0; m < 4; ++m)
        #pragma unroll
        for (int n = 0; n < 7; ++n)
            acc[m][n] = (float4v){0.f, 0.f, 0.f, 0.f};

    const unsigned short* xnb = X2 + (long)n_img * (IMG * CIN);

    for (int ci_hi = 0; ci_hi < 4; ++ci_hi) {
        __syncthreads();   // protect Bs from previous iteration's readers

        // ---- stage raw x tile: 4 rows x 58 cols x 32 ci, halo -> 0 ----
        #pragma unroll
        for (int it = 0; it < 4; ++it) {
            int idx = it * 256 + tid;      // 0..1023, valid < 928
            int ci8 = idx & 3;
            int rc  = idx >> 2;            // r*58 + c, valid < 232
            if (rc < 232) {
                int r = rc / 58;
                int c = rc - r * 58;
                int h = h0 - 1 + r;
                int w = c - 1;
                uint4 v = make_uint4(0u, 0u, 0u, 0u);
                if ((unsigned)h < 56u && (unsigned)w < 56u)
                    v = *(const uint4*)(xnb + ((h * HWID + w) * CIN + ci_hi * 32 + ci8 * 8));
                *(uint4*)(&Bs[rc * CSTR + ci8 * 8]) = v;
            }
        }
        __syncthreads();

        // ---- 9 khw positions, NO barriers (Bs read-only here) ----
        #pragma unroll
        for (int khw = 0; khw < 9; ++khw) {
            const int kh = khw / 3, kw = khw - (khw / 3) * 3;
            const int step = ci_hi * 9 + khw;
            short8 a[4], b[7];
            #pragma unroll
            for (int m = 0; m < 4; ++m)
                a[m] = *(const short8*)(wbase + step * 8192 + m * 512);
            #pragma unroll
            for (int n = 0; n < 7; ++n)
                b[n] = *(const short8*)(&Bs[boff[n] + (kh * 58 + kw) * CSTR]);
            #pragma unroll
            for (int m = 0; m < 4; ++m)
                #pragma unroll
                for (int n = 0; n < 7; ++n)
                    acc[m][n] = __builtin_amdgcn_mfma_f32_16x16x32_bf16(a[m], b[n], acc[m][n], 0, 0, 0);
        }
    }

    // ---- epilogue: C/D layout col(p)=lane&15, row(co)=quad*4+reg ----
    float* obase = out + (long)n_img * (COUT * IMG) + h0 * HWID;
    #pragma unroll
    for (int m = 0; m < 4; ++m) {
        #pragma unroll
        for (int r = 0; r < 4; ++r) {
            int co = wv * 64 + m * 16 + quad * 4 + r;
            float* orow = obase + (long)co * IMG;
            #pragma unroll
            for (int n = 0; n < 7; ++n)
                orow[n * 16 + l15] = acc[m][n][r];
        }
    }
}

extern "C" void kernel_launch(void* const* d_in, const int* in_sizes, int n_in,
                              void* d_out, int out_size, void* d_ws, size_t ws_size,
                              hipStream_t stream) {
    const float* x  = (const float*)d_in[0];
    const float* wt = (const float*)d_in[1];
    float* out = (float*)d_out;

    unsigned short* X2 = (unsigned short*)d_ws;            // 12,845,056 shorts (NHWC bf16)
    unsigned short* W2 = X2 + (long)NIMG * CIN * IMG;      // 294,912 shorts

    prep_x_kernel<<<NIMG * 4 * 49, 256, 0, stream>>>(x, X2);
    prep_w_kernel<<<(COUT * CIN * 9) / 256, 256, 0, stream>>>(wt, W2);
    conv_mfma_kernel<<<896, 256, 0, stream>>>(X2, W2, out);
}